// Round 7
// baseline (198.314 us; speedup 1.0000x reference)
//
#include <hip/hip_runtime.h>
#include <hip/hip_bf16.h>

#define B_ 4
#define T_ 4096
#define C_ 1024
#define H_ 64

typedef __bf16 bf16x8 __attribute__((ext_vector_type(8)));
typedef float f32x4 __attribute__((ext_vector_type(4)));
typedef unsigned short u16x8 __attribute__((ext_vector_type(8)));

union Frag8 { uint4 u; bf16x8 b; u16x8 s; };

__device__ inline unsigned short bfbits(float f) {
  union { __hip_bfloat16 h; unsigned short u; } cv;
  cv.h = __float2bfloat16(f);
  return cv.u;
}

__device__ inline float b2f(unsigned short u) {
  union { unsigned int i; float f; } c; c.i = ((unsigned int)u) << 16; return c.f;
}

__device__ inline bf16x8 ldb8(const unsigned short* p) {
  Frag8 f; f.u = *(const uint4*)p; return f.b;
}

__device__ inline bf16x8 asbf(uint4 u) { Frag8 f; f.u = u; return f.b; }

// pack two fp32 -> (bf16(a)) | (bf16(b)<<16), round-half-up, 3 VALU ops
__device__ inline unsigned pkbf(float a, float b) {
  union { float f; unsigned u; } ua, ub; ua.f = a; ub.f = b;
  return __builtin_amdgcn_perm(ub.u + 0x8000u, ua.u + 0x8000u, 0x07060302u);
}

__device__ inline Frag8 packA(float4 a0, float4 a1) {
  Frag8 af;
  af.s[0] = bfbits(a0.x); af.s[1] = bfbits(a0.y);
  af.s[2] = bfbits(a0.z); af.s[3] = bfbits(a0.w);
  af.s[4] = bfbits(a1.x); af.s[5] = bfbits(a1.y);
  af.s[6] = bfbits(a1.z); af.s[7] = bfbits(a1.w);
  return af;
}

// async global->LDS, 16B per lane; LDS dest = wave-uniform base + lane*16
__device__ inline void gload16(const void* g, void* l) {
  __builtin_amdgcn_global_load_lds(
      (const __attribute__((address_space(1))) unsigned int*)g,
      (__attribute__((address_space(3))) unsigned int*)l, 16, 0, 0);
}

// P^T (MFMA C layout, 4 kb-blocks) -> PV A-operand frags + 4 PV MFMAs
__device__ inline void pv_tile(const unsigned (*pk)[2], const uint4* vf,
                               int quad, int src0,
                               f32x4& o0, f32x4& o1, f32x4& o2, f32x4& o3) {
  const int kbsel = quad >> 1;
#pragma unroll
  for (int kb2 = 0; kb2 < 2; ++kb2) {
    int xA = __shfl((int)pk[2 * kb2][0], src0);
    int xB = __shfl((int)pk[2 * kb2 + 1][0], src0);
    int yA = __shfl((int)pk[2 * kb2][1], src0);
    int yB = __shfl((int)pk[2 * kb2 + 1][1], src0);
    int zA = __shfl((int)pk[2 * kb2][0], src0 + 16);
    int zB = __shfl((int)pk[2 * kb2 + 1][0], src0 + 16);
    int wA = __shfl((int)pk[2 * kb2][1], src0 + 16);
    int wB = __shfl((int)pk[2 * kb2 + 1][1], src0 + 16);
    Frag8 pf;
    pf.u.x = (unsigned)(kbsel ? xB : xA);
    pf.u.y = (unsigned)(kbsel ? yB : yA);
    pf.u.z = (unsigned)(kbsel ? zB : zA);
    pf.u.w = (unsigned)(kbsel ? wB : wA);
    o0 = __builtin_amdgcn_mfma_f32_16x16x32_bf16(pf.b, asbf(vf[kb2 * 4 + 0]), o0, 0, 0, 0);
    o1 = __builtin_amdgcn_mfma_f32_16x16x32_bf16(pf.b, asbf(vf[kb2 * 4 + 1]), o1, 0, 0, 0);
    o2 = __builtin_amdgcn_mfma_f32_16x16x32_bf16(pf.b, asbf(vf[kb2 * 4 + 2]), o2, 0, 0, 0);
    o3 = __builtin_amdgcn_mfma_f32_16x16x32_bf16(pf.b, asbf(vf[kb2 * 4 + 3]), o3, 0, 0, 0);
  }
}

// ---------------- k0: convert W (3 x [64,1024] fp32) to bf16 ----------------
__global__ __launch_bounds__(256) void wconv(const float* __restrict__ Wq,
                                             const float* __restrict__ Wk,
                                             const float* __restrict__ Wv,
                                             unsigned short* __restrict__ Wb) {
  int i = blockIdx.x * 256 + threadIdx.x;
  size_t e = (size_t)i * 4;
  const float* src = (e < 65536) ? (Wq + e)
                   : (e < 131072 ? (Wk + (e - 65536)) : (Wv + (e - 131072)));
  float4 v = *(const float4*)src;
  unsigned long long o =
      (unsigned long long)bfbits(v.x)
    | ((unsigned long long)bfbits(v.y) << 16)
    | ((unsigned long long)bfbits(v.z) << 32)
    | ((unsigned long long)bfbits(v.w) << 48);
  *(unsigned long long*)(Wb + e) = o;
}

// ---------------- k1: QKV projection GEMM, BK=128, coalesced LDS staging ----
// Block = 32 rows x 192 cols. x staged async into LDS (global-side XOR
// swizzle keeps coalescing, spreads LDS bank groups). __launch_bounds__(256,2)
// gives a 256-VGPR budget so the 12 W loads/period stay batch-issued (at 64
// regs the compiler serialized them at L3 latency -> the R5/R6 ~70us).
__global__ __launch_bounds__(256, 2) void qkv_proj(const float* __restrict__ x,
                                                   const unsigned short* __restrict__ Wb,
                                                   unsigned short* __restrict__ qkv,
                                                   unsigned short* __restrict__ Vt) {
  __shared__ float xs[4096];                      // 2 halves x 32 rows x 64 f32
  const int lane = threadIdx.x & 63;
  const int wave = threadIdx.x >> 6;
  const int q16 = lane & 15, quad = lane >> 4;
  const size_t row0 = (size_t)blockIdx.x * 32;

  const unsigned short* wp[3];
#pragma unroll
  for (int ct = 0; ct < 3; ++ct) {
    int gcol = wave * 48 + ct * 16;               // 0..176
    wp[ct] = Wb + (size_t)(gcol >> 6) * 65536
                + (size_t)((gcol & 63) + q16) * C_ + quad * 8;
  }

  const int sr = (lane >> 4);                     // row-within-issue-group
  const int sc_pos = lane & 15;                   // stored 16B-chunk position
  f32x4 acc[2][3] = {};

  for (int kc = 0; kc < C_; kc += 128) {
    __syncthreads();                              // readers of prev chunk done
#pragma unroll
    for (int ii = 0; ii < 4; ++ii) {
      int flat = wave * 4 + ii;                   // 0..15
      int h = flat >> 3, i = flat & 7;
      int r = i * 4 + sr;                         // tile row 0..31
      int sg = (sc_pos >> 1) ^ (r & 7);           // swizzled global superchunk
      const float* gp = x + (row0 + r) * C_ + kc + h * 64 + sg * 8 + (sc_pos & 1) * 4;
      gload16(gp, &xs[h * 2048 + i * 256]);
    }
    // W B-frags: 12 independent L2/L3 loads, batch-issued (one latency)
    uint4 wf[12];
#pragma unroll
    for (int ct = 0; ct < 3; ++ct)
#pragma unroll
      for (int hs = 0; hs < 4; ++hs)
        wf[ct * 4 + hs] = *(const uint4*)(wp[ct] + kc + hs * 32);
    __syncthreads();                              // staging visible
#pragma unroll
    for (int hs = 0; hs < 4; ++hs) {
#pragma unroll
      for (int rt = 0; rt < 2; ++rt) {
        int r = rt * 16 + q16;
        int p = (((hs & 1) * 4 + quad) ^ (r & 7)) * 8;
        const float* ap = &xs[(hs >> 1) * 2048 + r * 64 + p];
        float4 a0 = *(const float4*)ap;
        float4 a1 = *(const float4*)(ap + 4);
        Frag8 af = packA(a0, a1);
#pragma unroll
        for (int ct = 0; ct < 3; ++ct)
          acc[rt][ct] = __builtin_amdgcn_mfma_f32_16x16x32_bf16(
              af.b, asbf(wf[ct * 4 + hs]), acc[rt][ct], 0, 0, 0);
      }
    }
  }

  const int bb = (int)(blockIdx.x >> 7);          // 128 blocks per batch
#pragma unroll
  for (int rt = 0; rt < 2; ++rt) {
    const int t0 = (int)(row0 - (size_t)bb * T_) + rt * 16 + quad * 4;
#pragma unroll
    for (int ct = 0; ct < 3; ++ct) {
      int gcol = wave * 48 + ct * 16;
      int mat = gcol >> 6, h = (gcol & 63) + q16;
      if (mat == 2) {                             // V: store transposed
        ushort4 v;
        v.x = bfbits(acc[rt][ct][0]); v.y = bfbits(acc[rt][ct][1]);
        v.z = bfbits(acc[rt][ct][2]); v.w = bfbits(acc[rt][ct][3]);
        *(ushort4*)(Vt + ((size_t)bb * H_ + h) * T_ + t0) = v;
      } else {
        // Q pre-scaled by (1/sqrt(64)) * log2(e) -> softmax runs in exp2 domain
        float scale = (mat == 0) ? 0.18033688f : 1.0f;
#pragma unroll
        for (int r = 0; r < 4; ++r) {
          size_t row = row0 + rt * 16 + quad * 4 + r;
          qkv[(size_t)mat * 1048576 + row * H_ + h] = bfbits(acc[rt][ct][r] * scale);
        }
      }
    }
  }
}

// ---------------- k2: flash attention, single-shot softmax per wave ---------
// grid (1024, 8): x = global q-tile (b*256+qtl), y = 512-row k-chunk.
// Each wave: <=2 k-tiles as ONE 128-row softmax batch. ALL 32 K/V loads are
// hoisted to the top in consumption order; __launch_bounds__(256,2) gives the
// 256-VGPR budget needed to keep them in flight (at 56 VGPR the compiler
// serialized them -> R6's exposed-latency 80us).
__global__ __launch_bounds__(256, 2) void attn(const unsigned short* __restrict__ Q,
                                               const unsigned short* __restrict__ K,
                                               const unsigned short* __restrict__ Vt,
                                               float* __restrict__ part) {
  const int qt = blockIdx.x;                      // 0..1023
  const int qtl = qt & 255, b = qt >> 8;
  const int ki = (qtl >> 2) + 1;                  // total 64-row k-tiles
  const int c = blockIdx.y;
  if (c * 8 >= ki) return;
  const int e = (ki < c * 8 + 8) ? ki : c * 8 + 8;

  __shared__ float ml_s[2][4][16];
  __shared__ float o_s[4][16][68];
  const int lane = threadIdx.x & 63;
  const int wave = threadIdx.x >> 6;
  const int q16 = lane & 15, quad = lane >> 4;

  const unsigned short* Qb = Q + (size_t)b * T_ * H_;
  const unsigned short* Kb = K + (size_t)b * T_ * H_;
  const unsigned short* Vtb = Vt + (size_t)b * H_ * T_;

  const int q0 = qtl * 16;
  const int tA = c * 8 + wave;                    // wave's two k-tiles
  const int tB = tA + 4;                          // <=63 -> loads in-bounds
  const bool vA = tA < e, vB = tB < e;

  // ---- hoist ALL loads, in consumption order: Q, K(A), K(B), V(A), V(B) ----
  bf16x8 qf0 = ldb8(Qb + (size_t)(q0 + q16) * H_ + quad * 8);
  bf16x8 qf1 = ldb8(Qb + (size_t)(q0 + q16) * H_ + 32 + quad * 8);
  uint4 kfA[8], kfB[8], vfA[8], vfB[8];
#pragma unroll
  for (int kb = 0; kb < 4; ++kb) {
    const unsigned short* kp = Kb + (size_t)(tA * 64 + kb * 16 + q16) * H_ + quad * 8;
    kfA[2 * kb]     = *(const uint4*)kp;
    kfA[2 * kb + 1] = *(const uint4*)(kp + 32);
  }
#pragma unroll
  for (int kb = 0; kb < 4; ++kb) {
    const unsigned short* kp = Kb + (size_t)(tB * 64 + kb * 16 + q16) * H_ + quad * 8;
    kfB[2 * kb]     = *(const uint4*)kp;
    kfB[2 * kb + 1] = *(const uint4*)(kp + 32);
  }
#pragma unroll
  for (int kb2 = 0; kb2 < 2; ++kb2) {
    const unsigned short* vp = Vtb + (size_t)q16 * T_ + tA * 64 + kb2 * 32 + quad * 8;
#pragma unroll
    for (int j = 0; j < 4; ++j)
      vfA[kb2 * 4 + j] = *(const uint4*)(vp + (size_t)(16 * j) * T_);
  }
#pragma unroll
  for (int kb2 = 0; kb2 < 2; ++kb2) {
    const unsigned short* vp = Vtb + (size_t)q16 * T_ + tB * 64 + kb2 * 32 + quad * 8;
#pragma unroll
    for (int j = 0; j < 4; ++j)
      vfB[kb2 * 4 + j] = *(const uint4*)(vp + (size_t)(16 * j) * T_);
  }

  // ---- QK^T both tiles: S^T = K Q^T (C layout: kk=quad*4+reg, q=lane&15) ---
  f32x4 st[8];
#pragma unroll
  for (int kb = 0; kb < 4; ++kb) {
    f32x4 s = {0.f, 0.f, 0.f, 0.f};
    s = __builtin_amdgcn_mfma_f32_16x16x32_bf16(asbf(kfA[2 * kb]), qf0, s, 0, 0, 0);
    s = __builtin_amdgcn_mfma_f32_16x16x32_bf16(asbf(kfA[2 * kb + 1]), qf1, s, 0, 0, 0);
    st[kb] = s;
  }
#pragma unroll
  for (int kb = 0; kb < 4; ++kb) {
    f32x4 s = {0.f, 0.f, 0.f, 0.f};
    s = __builtin_amdgcn_mfma_f32_16x16x32_bf16(asbf(kfB[2 * kb]), qf0, s, 0, 0, 0);
    s = __builtin_amdgcn_mfma_f32_16x16x32_bf16(asbf(kfB[2 * kb + 1]), qf1, s, 0, 0, 0);
    st[4 + kb] = s;
  }

  // masks: causal diagonal (only last k-tile) + invalid-tile blanking
  const int q_abs = q0 + q16;
  if (tA == ki - 1) {
#pragma unroll
    for (int kb = 0; kb < 4; ++kb)
#pragma unroll
      for (int r = 0; r < 4; ++r)
        if (tA * 64 + kb * 16 + quad * 4 + r > q_abs) st[kb][r] = -3.0e38f;
  }
  if (tB == ki - 1) {
#pragma unroll
    for (int kb = 0; kb < 4; ++kb)
#pragma unroll
      for (int r = 0; r < 4; ++r)
        if (tB * 64 + kb * 16 + quad * 4 + r > q_abs) st[4 + kb][r] = -3.0e38f;
  }
  if (!vA) {
#pragma unroll
    for (int j = 0; j < 4; ++j)
#pragma unroll
      for (int r = 0; r < 4; ++r) st[j][r] = -3.0e38f;
  }
  if (!vB) {
#pragma unroll
    for (int j = 0; j < 4; ++j)
#pragma unroll
      for (int r = 0; r < 4; ++r) st[4 + j][r] = -3.0e38f;
  }

  // single max over all 8 frags + cross-quad reduce
  float m = fmaxf(fmaxf(st[0][0], st[0][1]), fmaxf(st[0][2], st[0][3]));
#pragma unroll
  for (int j = 1; j < 8; ++j)
    m = fmaxf(m, fmaxf(fmaxf(st[j][0], st[j][1]), fmaxf(st[j][2], st[j][3])));
  m = fmaxf(m, __shfl_xor(m, 16));
  m = fmaxf(m, __shfl_xor(m, 32));

  // one exp2 pass + cheap pack (single update from zero; no online rescale)
  float lsum = 0.f;
  unsigned pk[8][2];
#pragma unroll
  for (int j = 0; j < 8; ++j) {
    float p0 = exp2f(st[j][0] - m);
    float p1 = exp2f(st[j][1] - m);
    float p2 = exp2f(st[j][2] - m);
    float p3 = exp2f(st[j][3] - m);
    lsum += (p0 + p1) + (p2 + p3);
    pk[j][0] = pkbf(p0, p1);
    pk[j][1] = pkbf(p2, p3);
  }
  lsum += __shfl_xor(lsum, 16);
  lsum += __shfl_xor(lsum, 32);
  const float l = lsum;

  // PV both tiles (invalid tiles contribute exactly 0; fully-idle waves are
  // zeroed by beta=0 in the merge)
  f32x4 o0 = {0.f, 0.f, 0.f, 0.f}, o1 = o0, o2 = o0, o3 = o0;
  const int src0 = q16 + 32 * (quad & 1);
  pv_tile(&pk[0], vfA, quad, src0, o0, o1, o2, o3);
  pv_tile(&pk[4], vfB, quad, src0, o0, o1, o2, o3);

  // ---- in-block merge across the 4 waves (exp2 domain) ----
  if (quad == 0) { ml_s[0][wave][q16] = m; ml_s[1][wave][q16] = l; }
  __syncthreads();
  float M = fmaxf(fmaxf(ml_s[0][0][q16], ml_s[0][1][q16]),
                  fmaxf(ml_s[0][2][q16], ml_s[0][3][q16]));
  float beta = exp2f(m - M);                      // 0 for idle waves
  float b0 = __shfl(beta, quad * 4 + 0);
  float b1 = __shfl(beta, quad * 4 + 1);
  float b2 = __shfl(beta, quad * 4 + 2);
  float b3 = __shfl(beta, quad * 4 + 3);
  o0[0] *= b0; o0[1] *= b1; o0[2] *= b2; o0[3] *= b3;
  o1[0] *= b0; o1[1] *= b1; o1[2] *= b2; o1[3] *= b3;
  o2[0] *= b0; o2[1] *= b1; o2[2] *= b2; o2[3] *= b3;
  o3[0] *= b0; o3[1] *= b1; o3[2] *= b2; o3[3] *= b3;
#pragma unroll
  for (int r = 0; r < 4; ++r) {
    o_s[wave][quad * 4 + r][q16 + 0]  = o0[r];
    o_s[wave][quad * 4 + r][q16 + 16] = o1[r];
    o_s[wave][quad * 4 + r][q16 + 32] = o2[r];
    o_s[wave][quad * 4 + r][q16 + 48] = o3[r];
  }
  __syncthreads();

  const int t = threadIdx.x;
  const int row = t >> 4;
  const int col0 = (t & 15) * 4;
  float m0 = ml_s[0][0][row], m1 = ml_s[0][1][row];
  float m2 = ml_s[0][2][row], m3 = ml_s[0][3][row];
  float Mr = fmaxf(fmaxf(m0, m1), fmaxf(m2, m3));
  float lt = ml_s[1][0][row] * exp2f(m0 - Mr) + ml_s[1][1][row] * exp2f(m1 - Mr)
           + ml_s[1][2][row] * exp2f(m2 - Mr) + ml_s[1][3][row] * exp2f(m3 - Mr);
  float4 a0 = *(const float4*)&o_s[0][row][col0];
  float4 a1 = *(const float4*)&o_s[1][row][col0];
  float4 a2 = *(const float4*)&o_s[2][row][col0];
  float4 a3 = *(const float4*)&o_s[3][row][col0];
  // write unnormalized partial: O bf16 [16][64], then m[16], l[16] fp32
  float* P = part + (size_t)(qt * 8 + c) * 544;
  ushort4 ov;
  ov.x = bfbits(a0.x + a1.x + a2.x + a3.x);
  ov.y = bfbits(a0.y + a1.y + a2.y + a3.y);
  ov.z = bfbits(a0.z + a1.z + a2.z + a3.z);
  ov.w = bfbits(a0.w + a1.w + a2.w + a3.w);
  *((ushort4*)P + t) = ov;
  if ((t & 15) == 0) { P[512 + row] = Mr; P[528 + row] = lt; }
}

// ---------------- k3: merge <=8 partials per q-tile, normalize, store -------
__global__ __launch_bounds__(256) void attn_merge(const float* __restrict__ part,
                                                  float* __restrict__ out) {
  const int qt = blockIdx.x;                      // 0..1023
  const int qtl = qt & 255, b = qt >> 8;
  const int ki = (qtl >> 2) + 1;
  const int nch = (ki + 7) >> 3;
  const int t = threadIdx.x;
  const int row = t >> 4, col0 = (t & 15) * 4;
  const float* P0 = part + (size_t)qt * 8 * 544;
  float M = -3.0e38f;
  for (int c2 = 0; c2 < nch; ++c2) M = fmaxf(M, P0[c2 * 544 + 512 + row]);
  float L = 0.f;
  float ax = 0.f, ay = 0.f, az = 0.f, aw = 0.f;
  for (int c2 = 0; c2 < nch; ++c2) {
    const float* P = P0 + c2 * 544;
    float w = exp2f(P[512 + row] - M);
    L += w * P[528 + row];
    ushort4 ov = *((const ushort4*)P + t);
    ax += w * b2f(ov.x); ay += w * b2f(ov.y);
    az += w * b2f(ov.z); aw += w * b2f(ov.w);
  }
  float inv = 1.0f / L;
  float4 r = {ax * inv, ay * inv, az * inv, aw * inv};
  *(float4*)(out + ((size_t)b * T_ + qtl * 16 + row) * H_ + col0) = r;
}

extern "C" void kernel_launch(void* const* d_in, const int* in_sizes, int n_in,
                              void* d_out, int out_size, void* d_ws, size_t ws_size,
                              hipStream_t stream) {
  const float* x  = (const float*)d_in[0];
  const float* Wq = (const float*)d_in[1];
  const float* Wk = (const float*)d_in[2];
  const float* Wv = (const float*)d_in[3];
  float* out = (float*)d_out;
  unsigned short* ws = (unsigned short*)d_ws;

  // ws layout (ushort units):
  //   [0, 196608)           Wb  (Q|K|V bf16 weights)
  //   [196608, +2*1048576)  Q,K bf16 [B*T][64]  (Q pre-scaled, exp2 domain)
  //   next 1048576          Vt bf16 [B][64][T]
  //   next (float region)   partials: 8192 x 544 fp32 words (~17.8 MB)
  unsigned short* Wb  = ws;
  unsigned short* qkv = ws + 196608;
  unsigned short* Vt  = qkv + (size_t)2 * 1048576;
  float* part = (float*)(ws + 196608 + (size_t)3 * 1048576);

  wconv<<<192, 256, 0, stream>>>(Wq, Wk, Wv, Wb);
  qkv_proj<<<512, 256, 0, stream>>>(x, Wb, qkv, Vt);
  attn<<<dim3(1024, 8), 256, 0, stream>>>(qkv, qkv + 1048576, Vt, part);
  attn_merge<<<1024, 256, 0, stream>>>(part, out);
}

// Round 8
// 169.668 us; speedup vs baseline: 1.1688x; 1.1688x over previous
//
#include <hip/hip_runtime.h>
#include <hip/hip_bf16.h>

#define B_ 4
#define T_ 4096
#define C_ 1024
#define H_ 64

typedef __bf16 bf16x8 __attribute__((ext_vector_type(8)));
typedef float f32x4 __attribute__((ext_vector_type(4)));
typedef unsigned short u16x8 __attribute__((ext_vector_type(8)));

union Frag8 { uint4 u; bf16x8 b; u16x8 s; };

__device__ inline unsigned short bfbits(float f) {
  union { __hip_bfloat16 h; unsigned short u; } cv;
  cv.h = __float2bfloat16(f);
  return cv.u;
}

__device__ inline float b2f(unsigned u) {
  union { unsigned i; float f; } c; c.i = u << 16; return c.f;
}

__device__ inline bf16x8 ldb8(const unsigned short* p) {
  Frag8 f; f.u = *(const uint4*)p; return f.b;
}

__device__ inline bf16x8 asbf(uint4 u) { Frag8 f; f.u = u; return f.b; }

// pack two fp32 -> (bf16(a)) | (bf16(b)<<16), round-half-up, 3 VALU ops
__device__ inline unsigned pkbf(float a, float b) {
  union { float f; unsigned u; } ua, ub; ua.f = a; ub.f = b;
  return __builtin_amdgcn_perm(ub.u + 0x8000u, ua.u + 0x8000u, 0x07060302u);
}

__device__ inline Frag8 packA(float4 a0, float4 a1) {
  Frag8 af;
  af.s[0] = bfbits(a0.x); af.s[1] = bfbits(a0.y);
  af.s[2] = bfbits(a0.z); af.s[3] = bfbits(a0.w);
  af.s[4] = bfbits(a1.x); af.s[5] = bfbits(a1.y);
  af.s[6] = bfbits(a1.z); af.s[7] = bfbits(a1.w);
  return af;
}

// async global->LDS, 16B per lane; LDS dest = wave-uniform base + lane*16
__device__ inline void gload16(const void* g, void* l) {
  __builtin_amdgcn_global_load_lds(
      (const __attribute__((address_space(1))) unsigned int*)g,
      (__attribute__((address_space(3))) unsigned int*)l, 16, 0, 0);
}

// ---------------- k0: convert W (3 x [64,1024] fp32) to bf16 ----------------
__global__ __launch_bounds__(256) void wconv(const float* __restrict__ Wq,
                                             const float* __restrict__ Wk,
                                             const float* __restrict__ Wv,
                                             unsigned short* __restrict__ Wb) {
  int i = blockIdx.x * 256 + threadIdx.x;
  size_t e = (size_t)i * 4;
  const float* src = (e < 65536) ? (Wq + e)
                   : (e < 131072 ? (Wk + (e - 65536)) : (Wv + (e - 131072)));
  float4 v = *(const float4*)src;
  unsigned long long o =
      (unsigned long long)bfbits(v.x)
    | ((unsigned long long)bfbits(v.y) << 16)
    | ((unsigned long long)bfbits(v.z) << 32)
    | ((unsigned long long)bfbits(v.w) << 48);
  *(unsigned long long*)(Wb + e) = o;
}

// ---------------- k1: QKV projection GEMM, fully async-staged ---------------
// Block = 32 rows x 192 cols; BK=64; 16 two-barrier periods (m97 structure).
// BOTH x and W are staged via global_load_lds (no register-batched loads left
// for the scheduler to serialize). Global side is contiguous per issue; 16B
// chunk index XOR-swizzled with row low bits (stays inside the cacheline) so
// LDS frag reads are bank-balanced.
__global__ __launch_bounds__(256) void qkv_proj(const float* __restrict__ x,
                                                const unsigned short* __restrict__ Wb,
                                                unsigned short* __restrict__ qkv,
                                                unsigned short* __restrict__ Vt) {
  __shared__ float xs[2048];                 // 32 rows x 64 f32 (8 KB)
  __shared__ unsigned short Wsh[12288];      // 192 rows x 64 halves (24 KB)
  const int lane = threadIdx.x & 63;
  const int wave = threadIdx.x >> 6;
  const int q16 = lane & 15, quad = lane >> 4;
  const int x7 = q16 & 7;
  const size_t row0 = (size_t)blockIdx.x * 32;

  const int sr = lane >> 4;                  // x-staging: row within group of 4
  const int sc_pos = lane & 15;              // x-staging: stored 16B-chunk pos
  const int rloc = lane >> 3;                // W-staging: row within group of 8
  const int cpos = lane & 7;                 // W-staging: stored 16B-chunk pos

  f32x4 acc[2][3] = {};

  for (int kc = 0; kc < C_; kc += 64) {
    __syncthreads();                         // readers of prev chunk done
    // ---- stage x: 8 issues (2/wave), rows i*4+sr, 32B-superchunk swizzle ---
#pragma unroll
    for (int ii = 0; ii < 2; ++ii) {
      int i = wave * 2 + ii;
      int r = i * 4 + sr;
      int sg = (sc_pos >> 1) ^ (r & 7);
      const float* gp = x + (row0 + r) * C_ + kc + sg * 8 + (sc_pos & 1) * 4;
      gload16(gp, &xs[i * 256]);
    }
    // ---- stage W: 24 issues (6/wave), rows 8j+rloc, chunk^rloc swizzle -----
#pragma unroll
    for (int jj = 0; jj < 6; ++jj) {
      int j = wave * 6 + jj;
      int g = j * 8 + rloc;                  // flat col 0..191
      const unsigned short* gp = Wb + (size_t)(g >> 6) * 65536
                                    + (size_t)(g & 63) * C_ + kc + (cpos ^ rloc) * 8;
      gload16(gp, &Wsh[j * 512]);
    }
    __syncthreads();                         // staging visible
#pragma unroll
    for (int s = 0; s < 2; ++s) {
      bf16x8 bf[3];
#pragma unroll
      for (int ct = 0; ct < 3; ++ct) {
        int g = wave * 48 + ct * 16 + q16;
        bf[ct] = ldb8(&Wsh[g * 64 + (((s * 4 + quad) ^ x7) * 8)]);
      }
#pragma unroll
      for (int rt = 0; rt < 2; ++rt) {
        int r = rt * 16 + q16;
        int p = ((s * 4 + quad) ^ (r & 7)) * 8;
        const float* ap = &xs[r * 64 + p];
        float4 a0 = *(const float4*)ap;
        float4 a1 = *(const float4*)(ap + 4);
        Frag8 af = packA(a0, a1);
#pragma unroll
        for (int ct = 0; ct < 3; ++ct)
          acc[rt][ct] = __builtin_amdgcn_mfma_f32_16x16x32_bf16(
              af.b, bf[ct], acc[rt][ct], 0, 0, 0);
      }
    }
  }

  const int bb = (int)(blockIdx.x >> 7);     // 128 blocks per batch
#pragma unroll
  for (int rt = 0; rt < 2; ++rt) {
    const int t0 = (int)(row0 - (size_t)bb * T_) + rt * 16 + quad * 4;
#pragma unroll
    for (int ct = 0; ct < 3; ++ct) {
      int gcol = wave * 48 + ct * 16;
      int mat = gcol >> 6, h = (gcol & 63) + q16;
      if (mat == 2) {                        // V: store transposed
        ushort4 v;
        v.x = bfbits(acc[rt][ct][0]); v.y = bfbits(acc[rt][ct][1]);
        v.z = bfbits(acc[rt][ct][2]); v.w = bfbits(acc[rt][ct][3]);
        *(ushort4*)(Vt + ((size_t)bb * H_ + h) * T_ + t0) = v;
      } else {
        // Q pre-scaled by (1/sqrt(64))*log2(e) -> softmax in exp2 domain
        float scale = (mat == 0) ? 0.18033688f : 1.0f;
#pragma unroll
        for (int r = 0; r < 4; ++r) {
          size_t row = row0 + rt * 16 + quad * 4 + r;
          qkv[(size_t)mat * 1048576 + row * H_ + h] = bfbits(acc[rt][ct][r] * scale);
        }
      }
    }
  }
}

// ---------------- k2: flash attention, block-shared LDS K/V tiles -----------
// grid (256, 8): x -> (b, qblk reversed), y = 512-col k-chunk. Block = 64
// q-rows (wave w owns rows qblk*64+w*16..+15). Per k-tile (64 rows): K and V
// staged ONCE per block via global_load_lds (row-major, chunk^row swizzle,
// bank-balanced); all 4 waves consume from LDS with online softmax. Per-wave
// unnormalized partial (O bf16-packed + m,l) written to ws; no in-block merge.
__global__ __launch_bounds__(256) void attn(const unsigned short* __restrict__ Q,
                                            const unsigned short* __restrict__ K,
                                            const unsigned short* __restrict__ Vt,
                                            float* __restrict__ part) {
  const int b = blockIdx.x >> 6;
  const int qblk = 63 - (blockIdx.x & 63);   // big triangles dispatch first
  const int ki = qblk + 1;                   // total 64-row k-tiles
  const int c = blockIdx.y;
  const int c8 = c * 8;
  if (c8 >= ki) return;
  const int kend = (ki < c8 + 8) ? ki : c8 + 8;

  __shared__ unsigned short Ks[4096];        // 64 krows x 64 halves (8 KB)
  __shared__ unsigned short Vs[4096];        // 64 hrows x 64 halves (8 KB)
  const int lane = threadIdx.x & 63;
  const int wave = threadIdx.x >> 6;
  const int q16 = lane & 15, quad = lane >> 4;
  const int x7 = q16 & 7;
  const int rloc = lane >> 3, cpos = lane & 7;

  const unsigned short* Qb = Q + (size_t)b * T_ * H_;
  const unsigned short* Kb = K + (size_t)b * T_ * H_;
  const unsigned short* Vtb = Vt + (size_t)b * H_ * T_;

  const int q0w = qblk * 64 + wave * 16;     // this wave's q-rows
  bf16x8 qf0 = ldb8(Qb + (size_t)(q0w + q16) * H_ + quad * 8);
  bf16x8 qf1 = ldb8(Qb + (size_t)(q0w + q16) * H_ + 32 + quad * 8);

  f32x4 o0 = {0.f, 0.f, 0.f, 0.f}, o1 = o0, o2 = o0, o3 = o0;
  float m = -3.0e38f, l = 0.0f;
  const int q_abs = q0w + q16;
  const int src0 = q16 + 32 * (quad & 1);
  const int kbsel = quad >> 1;

  for (int kt = c8; kt < kend; ++kt) {
    const int kkb = kt * 64;
    __syncthreads();                         // prev tile's readers done
    // ---- stage K (8 issues) + V (8 issues), 4 per wave ----
#pragma unroll
    for (int ii = 0; ii < 2; ++ii) {
      int i = wave * 2 + ii;
      gload16(Kb + (size_t)(kkb + i * 8 + rloc) * H_ + (cpos ^ rloc) * 8,
              &Ks[i * 512]);
      gload16(Vtb + (size_t)(i * 8 + rloc) * T_ + kkb + (cpos ^ rloc) * 8,
              &Vs[i * 512]);
    }
    __syncthreads();                         // staging visible

    // ---- QK^T: S^T = K Q^T (C layout: kk=quad*4+reg, q=q16) ----
    f32x4 st[4];
#pragma unroll
    for (int kb = 0; kb < 4; ++kb) {
      bf16x8 ka0 = ldb8(&Ks[(kb * 16 + q16) * 64 + ((quad ^ x7) * 8)]);
      bf16x8 ka1 = ldb8(&Ks[(kb * 16 + q16) * 64 + (((quad + 4) ^ x7) * 8)]);
      f32x4 s = {0.f, 0.f, 0.f, 0.f};
      s = __builtin_amdgcn_mfma_f32_16x16x32_bf16(ka0, qf0, s, 0, 0, 0);
      s = __builtin_amdgcn_mfma_f32_16x16x32_bf16(ka1, qf1, s, 0, 0, 0);
      st[kb] = s;
    }
    if (kt == ki - 1) {                      // diagonal tile: causal mask
#pragma unroll
      for (int kb = 0; kb < 4; ++kb)
#pragma unroll
        for (int r = 0; r < 4; ++r)
          if (kkb + kb * 16 + quad * 4 + r > q_abs) st[kb][r] = -3.0e38f;
    }

    // ---- online softmax (exp2 domain) ----
    float mloc = fmaxf(fmaxf(st[0][0], st[0][1]), fmaxf(st[0][2], st[0][3]));
#pragma unroll
    for (int kb = 1; kb < 4; ++kb)
      mloc = fmaxf(mloc, fmaxf(fmaxf(st[kb][0], st[kb][1]), fmaxf(st[kb][2], st[kb][3])));
    mloc = fmaxf(mloc, __shfl_xor(mloc, 16));
    mloc = fmaxf(mloc, __shfl_xor(mloc, 32));
    float mnew = fmaxf(m, mloc);
    float alpha = exp2f(m - mnew);
    float lsum = 0.f;
    unsigned pk[4][2];
#pragma unroll
    for (int kb = 0; kb < 4; ++kb) {
      float p0 = exp2f(st[kb][0] - mnew);
      float p1 = exp2f(st[kb][1] - mnew);
      float p2 = exp2f(st[kb][2] - mnew);
      float p3 = exp2f(st[kb][3] - mnew);
      lsum += (p0 + p1) + (p2 + p3);
      pk[kb][0] = pkbf(p0, p1);
      pk[kb][1] = pkbf(p2, p3);
    }
    lsum += __shfl_xor(lsum, 16);
    lsum += __shfl_xor(lsum, 32);
    l = l * alpha + lsum;
    m = mnew;
    // rescale O: o-frag row = quad*4+r; alpha indexed by q16
    float ar0 = __shfl(alpha, quad * 4 + 0);
    float ar1 = __shfl(alpha, quad * 4 + 1);
    float ar2 = __shfl(alpha, quad * 4 + 2);
    float ar3 = __shfl(alpha, quad * 4 + 3);
    o0[0] *= ar0; o0[1] *= ar1; o0[2] *= ar2; o0[3] *= ar3;
    o1[0] *= ar0; o1[1] *= ar1; o1[2] *= ar2; o1[3] *= ar3;
    o2[0] *= ar0; o2[1] *= ar1; o2[2] *= ar2; o2[3] *= ar3;
    o3[0] *= ar0; o3[1] *= ar1; o3[2] *= ar2; o3[3] *= ar3;

    // ---- P^T -> A-layout (half-quad exchange) + PV from LDS V ----
#pragma unroll
    for (int kb2 = 0; kb2 < 2; ++kb2) {
      int xA = __shfl((int)pk[2 * kb2][0], src0);
      int xB = __shfl((int)pk[2 * kb2 + 1][0], src0);
      int yA = __shfl((int)pk[2 * kb2][1], src0);
      int yB = __shfl((int)pk[2 * kb2 + 1][1], src0);
      int zA = __shfl((int)pk[2 * kb2][0], src0 + 16);
      int zB = __shfl((int)pk[2 * kb2 + 1][0], src0 + 16);
      int wA = __shfl((int)pk[2 * kb2][1], src0 + 16);
      int wB = __shfl((int)pk[2 * kb2 + 1][1], src0 + 16);
      Frag8 pf;
      pf.u.x = (unsigned)(kbsel ? xB : xA);
      pf.u.y = (unsigned)(kbsel ? yB : yA);
      pf.u.z = (unsigned)(kbsel ? zB : zA);
      pf.u.w = (unsigned)(kbsel ? wB : wA);
      int vp = ((kb2 * 4 + quad) ^ x7) * 8;
      bf16x8 v0 = ldb8(&Vs[(q16 + 0)  * 64 + vp]);
      bf16x8 v1 = ldb8(&Vs[(q16 + 16) * 64 + vp]);
      bf16x8 v2 = ldb8(&Vs[(q16 + 32) * 64 + vp]);
      bf16x8 v3 = ldb8(&Vs[(q16 + 48) * 64 + vp]);
      o0 = __builtin_amdgcn_mfma_f32_16x16x32_bf16(pf.b, v0, o0, 0, 0, 0);
      o1 = __builtin_amdgcn_mfma_f32_16x16x32_bf16(pf.b, v1, o1, 0, 0, 0);
      o2 = __builtin_amdgcn_mfma_f32_16x16x32_bf16(pf.b, v2, o2, 0, 0, 0);
      o3 = __builtin_amdgcn_mfma_f32_16x16x32_bf16(pf.b, v3, o3, 0, 0, 0);
    }
  }

  // ---- per-wave partial write: O bf16-pair-packed i-major + m,l fp32 ----
  // value(row=quad*4+r, col=q16+16c) = o_c[r]; word[ip*64+lane] packs i=2ip,2ip+1
  const int qtl = qblk * 4 + wave;
  float* Pf = part + ((size_t)((b << 8) + qtl) * 8 + c) * 544;
  unsigned* Pw = (unsigned*)Pf;
  Pw[0 * 64 + lane] = pkbf(o0[0], o0[1]);
  Pw[1 * 64 + lane] = pkbf(o0[2], o0[3]);
  Pw[2 * 64 + lane] = pkbf(o1[0], o1[1]);
  Pw[3 * 64 + lane] = pkbf(o1[2], o1[3]);
  Pw[4 * 64 + lane] = pkbf(o2[0], o2[1]);
  Pw[5 * 64 + lane] = pkbf(o2[2], o2[3]);
  Pw[6 * 64 + lane] = pkbf(o3[0], o3[1]);
  Pw[7 * 64 + lane] = pkbf(o3[2], o3[3]);
  if (quad == 0) { Pf[512 + q16] = m; Pf[528 + q16] = l; }
}

// ---------------- k3: merge <=8 partials per q-tile, normalize, store -------
__global__ __launch_bounds__(256) void attn_merge(const float* __restrict__ part,
                                                  float* __restrict__ out) {
  const int qt = blockIdx.x;                 // 0..1023
  const int qtl = qt & 255, b = qt >> 8;
  const int ki = (qtl >> 2) + 1;             // 64-row k-tiles
  const int nch = (ki + 7) >> 3;
  const int t = threadIdx.x;
  const int row = t >> 4, col0 = (t & 15) * 4;
  const int i = (col0 >> 4) * 4 + (row & 3); // packed index (fixed over 4 cols)
  const int lane0 = (row >> 2) * 16 + (col0 & 15);
  const int sh = 16 * (i & 1);
  const float* P0 = part + (size_t)qt * 8 * 544;
  float M = -3.0e38f;
  for (int c2 = 0; c2 < nch; ++c2) M = fmaxf(M, P0[c2 * 544 + 512 + row]);
  float L = 0.f;
  float ax = 0.f, ay = 0.f, az = 0.f, aw = 0.f;
  for (int c2 = 0; c2 < nch; ++c2) {
    const float* P = P0 + c2 * 544;
    float w = exp2f(P[512 + row] - M);
    L += w * P[528 + row];
    const unsigned* Pw = (const unsigned*)P;
    uint4 wd = *(const uint4*)&Pw[(i >> 1) * 64 + lane0];
    ax += w * b2f((wd.x >> sh) & 0xffffu);
    ay += w * b2f((wd.y >> sh) & 0xffffu);
    az += w * b2f((wd.z >> sh) & 0xffffu);
    aw += w * b2f((wd.w >> sh) & 0xffffu);
  }
  float inv = 1.0f / L;
  float4 r = {ax * inv, ay * inv, az * inv, aw * inv};
  *(float4*)(out + ((size_t)b * T_ + qtl * 16 + row) * H_ + col0) = r;
}

extern "C" void kernel_launch(void* const* d_in, const int* in_sizes, int n_in,
                              void* d_out, int out_size, void* d_ws, size_t ws_size,
                              hipStream_t stream) {
  const float* x  = (const float*)d_in[0];
  const float* Wq = (const float*)d_in[1];
  const float* Wk = (const float*)d_in[2];
  const float* Wv = (const float*)d_in[3];
  float* out = (float*)d_out;
  unsigned short* ws = (unsigned short*)d_ws;

  // ws layout (ushort units):
  //   [0, 196608)           Wb  (Q|K|V bf16 weights)
  //   [196608, +2*1048576)  Q,K bf16 [B*T][64]  (Q pre-scaled, exp2 domain)
  //   next 1048576          Vt bf16 [B][64][T]
  //   next (float region)   partials: 8192 x 544 fp32 words (~17.8 MB)
  unsigned short* Wb  = ws;
  unsigned short* qkv = ws + 196608;
  unsigned short* Vt  = qkv + (size_t)2 * 1048576;
  float* part = (float*)(ws + 196608 + (size_t)3 * 1048576);

  wconv<<<192, 256, 0, stream>>>(Wq, Wk, Wv, Wb);
  qkv_proj<<<512, 256, 0, stream>>>(x, Wb, qkv, Vt);
  attn<<<dim3(256, 8), 256, 0, stream>>>(qkv, qkv + 1048576, Vt, part);
  attn_merge<<<1024, 256, 0, stream>>>(part, out);
}